// Round 1
// baseline (165.155 us; speedup 1.0000x reference)
//
#include <hip/hip_runtime.h>
#include <hip/hip_bf16.h>

// Problem constants (from reference)
#define NB    4
#define LQ    3840
#define DMODEL 256
#define NH    8
#define NL    4
#define NP    4
#define DH    32
#define LIN   3840          // sum(SHAPES)
#define NROWS (NB * LQ)     // 15360 (== NB*LIN too)

// ---------------- generic f32 GEMM: C[:, coff:coff+N] = A(MxK) @ W(KxN) + bias ----------------
#define BM 64
#define BN 64
#define BK 16

__global__ __launch_bounds__(256) void gemm_f32(
    const float* __restrict__ A, const float* __restrict__ W,
    const float* __restrict__ bias, float* __restrict__ C,
    int M, int N, int K, int ldc, int coff)
{
    __shared__ float As[BK][BM + 4];   // stride 68 floats: write-conflict-light, 16B-aligned rows
    __shared__ float Bs[BK][BN + 4];

    const int t  = threadIdx.x;
    const int tx = t & 15;
    const int ty = t >> 4;
    const int m0 = blockIdx.y * BM;
    const int n0 = blockIdx.x * BN;

    // load mapping
    const int lar = t >> 2;          // A row in tile 0..63
    const int lac = (t & 3) * 4;     // A k-offset {0,4,8,12}
    const int lbr = t >> 4;          // B k-row 0..15
    const int lbc = (t & 15) * 4;    // B col offset 0..60

    float acc[4][4] = {};

    for (int k0 = 0; k0 < K; k0 += BK) {
        const float4 av = *reinterpret_cast<const float4*>(
            A + (size_t)(m0 + lar) * K + k0 + lac);
        As[lac + 0][lar] = av.x;
        As[lac + 1][lar] = av.y;
        As[lac + 2][lar] = av.z;
        As[lac + 3][lar] = av.w;

        const float4 bv = *reinterpret_cast<const float4*>(
            W + (size_t)(k0 + lbr) * N + n0 + lbc);
        *reinterpret_cast<float4*>(&Bs[lbr][lbc]) = bv;

        __syncthreads();

        #pragma unroll
        for (int k = 0; k < BK; ++k) {
            float a[4], b[4];
            *reinterpret_cast<float4*>(a) = *reinterpret_cast<const float4*>(&As[k][ty * 4]);
            *reinterpret_cast<float4*>(b) = *reinterpret_cast<const float4*>(&Bs[k][tx * 4]);
            #pragma unroll
            for (int i = 0; i < 4; ++i)
                #pragma unroll
                for (int j = 0; j < 4; ++j)
                    acc[i][j] += a[i] * b[j];
        }
        __syncthreads();
    }

    #pragma unroll
    for (int i = 0; i < 4; ++i) {
        const int row = m0 + ty * 4 + i;
        #pragma unroll
        for (int j = 0; j < 4; ++j) {
            const int col = n0 + tx * 4 + j;
            C[(size_t)row * ldc + coff + col] = acc[i][j] + bias[col];
        }
    }
}

// ---------------- fused softmax + deformable sampling ----------------
// One block per (n, q). Reads its offattn row into LDS, then OVERWRITES the
// same row with the attention output (safe: only-own-row, read precedes barrier).
__global__ __launch_bounds__(256) void sample_k(
    const float* __restrict__ value,     // [NB][LIN][256]
    const float* __restrict__ offattn,   // [NROWS][256]  (cols 0..127 off, 128..255 attn logits)
    const float* __restrict__ refp,      // [NB][LQ][NL][1]
    const int*   __restrict__ shapes,    // [NL]
    const int*   __restrict__ starts,    // [NL]
    float*       __restrict__ outattn)   // [NROWS][256] (may alias offattn)
{
    __shared__ float row[256];
    __shared__ float refs[NL];
    __shared__ int   shp[NL], stt[NL];

    const int t = threadIdx.x;
    const int b = blockIdx.x;            // n*LQ + q
    const int n = b / LQ;
    const size_t rowbase = (size_t)b * 256;

    row[t] = offattn[rowbase + t];
    if (t < NL) {
        refs[t] = refp[(size_t)b * NL + t];
        shp[t]  = shapes[t];
        stt[t]  = starts[t];
    }
    __syncthreads();

    const int h = t >> 5;
    const int d = t & 31;

    const float* lg = &row[128 + h * 16];
    float mx = lg[0];
    #pragma unroll
    for (int i = 1; i < 16; ++i) mx = fmaxf(mx, lg[i]);
    float sum = 0.f;
    #pragma unroll
    for (int i = 0; i < 16; ++i) sum += __expf(lg[i] - mx);
    const float rsum = 1.f / sum;

    const float* vbase = value + (size_t)n * LIN * DMODEL + h * DH + d;

    float acc = 0.f;
    #pragma unroll
    for (int l = 0; l < NL; ++l) {
        const float T   = (float)shp[l];
        const float ref = refs[l];
        const int Tm1 = shp[l] - 1;
        const int st  = stt[l];
        #pragma unroll
        for (int p = 0; p < NP; ++p) {
            const int s = l * NP + p;
            const float aw  = __expf(lg[s] - mx) * rsum;
            const float off = row[h * 16 + s];
            // mimic reference rounding: loc = ref + off/T; c = loc*T - 0.5
            const float loc = ref + off / T;
            const float c   = loc * T - 0.5f;
            const float fl  = floorf(c);
            const float w   = c - fl;
            const int i0 = (int)fl;
            const int j0 = min(max(i0, 0), Tm1);
            const int j1 = min(max(i0 + 1, 0), Tm1);
            const float v0 = vbase[(size_t)(st + j0) * DMODEL];
            const float v1 = vbase[(size_t)(st + j1) * DMODEL];
            acc += aw * ((1.f - w) * v0 + w * v1);
        }
    }
    outattn[rowbase + t] = acc;
}

extern "C" void kernel_launch(void* const* d_in, const int* in_sizes, int n_in,
                              void* d_out, int out_size, void* d_ws, size_t ws_size,
                              hipStream_t stream) {
    const float* query  = (const float*)d_in[0];
    const float* refp   = (const float*)d_in[1];
    const float* inflat = (const float*)d_in[2];
    const int*   shapes = (const int*)d_in[3];
    const int*   starts = (const int*)d_in[4];
    const float* W_off  = (const float*)d_in[5];
    const float* b_off  = (const float*)d_in[6];
    const float* W_attn = (const float*)d_in[7];
    const float* b_attn = (const float*)d_in[8];
    const float* W_val  = (const float*)d_in[9];
    const float* b_val  = (const float*)d_in[10];
    const float* W_out  = (const float*)d_in[11];
    const float* b_out  = (const float*)d_in[12];
    float* out = (float*)d_out;

    float* value   = (float*)d_ws;                         // NROWS*256 f32 = 15.7 MB
    float* offattn = value + (size_t)NROWS * DMODEL;       // NROWS*256 f32 = 15.7 MB

    const dim3 blk(256);

    // value = input_flatten @ W_val + b_val
    gemm_f32<<<dim3(DMODEL / BN, NROWS / BM), blk, 0, stream>>>(
        inflat, W_val, b_val, value, NROWS, DMODEL, DMODEL, DMODEL, 0);

    // offattn[:, :128] = query @ W_off + b_off
    gemm_f32<<<dim3(128 / BN, NROWS / BM), blk, 0, stream>>>(
        query, W_off, b_off, offattn, NROWS, 128, DMODEL, DMODEL, 0);

    // offattn[:, 128:] = query @ W_attn + b_attn
    gemm_f32<<<dim3(128 / BN, NROWS / BM), blk, 0, stream>>>(
        query, W_attn, b_attn, offattn, NROWS, 128, DMODEL, DMODEL, 128);

    // softmax + sampling, in-place over offattn rows
    sample_k<<<NROWS, blk, 0, stream>>>(value, offattn, refp, shapes, starts, offattn);

    // out = outattn @ W_out + b_out
    gemm_f32<<<dim3(DMODEL / BN, NROWS / BM), blk, 0, stream>>>(
        offattn, W_out, b_out, out, NROWS, DMODEL, DMODEL, DMODEL, 0);
}

// Round 2
// 131.254 us; speedup vs baseline: 1.2583x; 1.2583x over previous
//
#include <hip/hip_runtime.h>
#include <hip/hip_bf16.h>

// Problem constants (from reference)
#define NB    4
#define LQ    3840
#define DMODEL 256
#define NH    8
#define NL    4
#define NP    4
#define DH    32
#define LIN   3840          // sum(SHAPES)
#define NROWS (NB * LQ)     // 15360

// ---------------- generic f32 GEMM: C[:, coff:coff+N] = A(MxK) @ W(KxN) + bias ----------------
#define BM 64
#define BN 64
#define BK 16

__global__ __launch_bounds__(256) void gemm_f32(
    const float* __restrict__ A, const float* __restrict__ W,
    const float* __restrict__ bias, float* __restrict__ C,
    int M, int N, int K, int ldc, int coff)
{
    __shared__ float As[BK][BM + 4];
    __shared__ float Bs[BK][BN + 4];

    const int t  = threadIdx.x;
    const int tx = t & 15;
    const int ty = t >> 4;
    const int m0 = blockIdx.y * BM;
    const int n0 = blockIdx.x * BN;

    const int lar = t >> 2;          // A row in tile 0..63
    const int lac = (t & 3) * 4;     // A k-offset {0,4,8,12}
    const int lbr = t >> 4;          // B k-row 0..15
    const int lbc = (t & 15) * 4;    // B col offset 0..60

    float acc[4][4] = {};

    for (int k0 = 0; k0 < K; k0 += BK) {
        const float4 av = *reinterpret_cast<const float4*>(
            A + (size_t)(m0 + lar) * K + k0 + lac);
        As[lac + 0][lar] = av.x;
        As[lac + 1][lar] = av.y;
        As[lac + 2][lar] = av.z;
        As[lac + 3][lar] = av.w;

        const float4 bv = *reinterpret_cast<const float4*>(
            W + (size_t)(k0 + lbr) * N + n0 + lbc);
        *reinterpret_cast<float4*>(&Bs[lbr][lbc]) = bv;

        __syncthreads();

        #pragma unroll
        for (int k = 0; k < BK; ++k) {
            float a[4], b[4];
            *reinterpret_cast<float4*>(a) = *reinterpret_cast<const float4*>(&As[k][ty * 4]);
            *reinterpret_cast<float4*>(b) = *reinterpret_cast<const float4*>(&Bs[k][tx * 4]);
            #pragma unroll
            for (int i = 0; i < 4; ++i)
                #pragma unroll
                for (int j = 0; j < 4; ++j)
                    acc[i][j] += a[i] * b[j];
        }
        __syncthreads();
    }

    #pragma unroll
    for (int i = 0; i < 4; ++i) {
        const int row = m0 + ty * 4 + i;
        #pragma unroll
        for (int j = 0; j < 4; ++j) {
            const int col = n0 + tx * 4 + j;
            C[(size_t)row * ldc + coff + col] = acc[i][j] + bias[col];
        }
    }
}

// ---------------- fused softmax + deformable sampling (phase-split) ----------------
// 4 rows per block. Phase 1: 32 threads (one per row,head) compute softmax +
// per-sample {w0,w1,rowidx0,rowidx1} into LDS. Phase 2: 256 threads (row,head,d4)
// accumulate float4 gathers. Output may alias offattn (rows staged to LDS first).
#define RPB 4

__global__ __launch_bounds__(256) void sample_k(
    const float* __restrict__ value,     // [NB][LIN][256]
    const float* __restrict__ offattn,   // [NROWS][256]  (cols 0..127 off, 128..255 attn logits)
    const float* __restrict__ refp,      // [NB][LQ][NL]
    const int*   __restrict__ shapes,    // [NL]
    const int*   __restrict__ starts,    // [NL]
    float*       __restrict__ outattn)   // [NROWS][256] (may alias offattn)
{
    __shared__ float row[RPB * 256];
    __shared__ float refs[RPB][NL];
    __shared__ float w0s[RPB][NH][16];
    __shared__ float w1s[RPB][NH][16];
    __shared__ int   a0s[RPB][NH][16];
    __shared__ int   a1s[RPB][NH][16];
    __shared__ int   shp[NL], stt[NL];

    const int t  = threadIdx.x;
    const int b0 = blockIdx.x * RPB;     // first row of this block

    // stage 4 contiguous offattn rows (1024 floats) as float4
    reinterpret_cast<float4*>(row)[t] =
        reinterpret_cast<const float4*>(offattn + (size_t)b0 * 256)[t];
    if (t < RPB * NL) {                  // 16 refs
        refs[t >> 2][t & 3] = refp[(size_t)(b0 + (t >> 2)) * NL + (t & 3)];
    }
    if (t >= 32 && t < 32 + NL) { shp[t - 32] = shapes[t - 32]; stt[t - 32] = starts[t - 32]; }
    __syncthreads();

    // ---- phase 1: scalar sample math, one thread per (r,h) ----
    if (t < RPB * NH) {
        const int r = t >> 3;
        const int h = t & 7;
        const int n = (b0 + r) / LQ;
        const int nbase = n * LIN;

        const float* lg = &row[r * 256 + 128 + h * 16];
        const float* of = &row[r * 256 + h * 16];

        float mx = lg[0];
        #pragma unroll
        for (int i = 1; i < 16; ++i) mx = fmaxf(mx, lg[i]);
        float e[16];
        float sum = 0.f;
        #pragma unroll
        for (int i = 0; i < 16; ++i) { e[i] = __expf(lg[i] - mx); sum += e[i]; }
        const float rsum = 1.f / sum;

        #pragma unroll
        for (int l = 0; l < NL; ++l) {
            const float T   = (float)shp[l];
            const float ref = refs[r][l];
            const int Tm1 = shp[l] - 1;
            const int st  = stt[l];
            #pragma unroll
            for (int p = 0; p < NP; ++p) {
                const int s = l * NP + p;
                const float aw  = e[s] * rsum;
                const float off = of[s];
                // mimic reference rounding: loc = ref + off/T; c = loc*T - 0.5
                const float loc = ref + off / T;
                const float c   = loc * T - 0.5f;
                const float fl  = floorf(c);
                const float w   = c - fl;
                const int i0 = (int)fl;
                const int j0 = min(max(i0, 0), Tm1);
                const int j1 = min(max(i0 + 1, 0), Tm1);
                w0s[r][h][s] = aw * (1.f - w);
                w1s[r][h][s] = aw * w;
                a0s[r][h][s] = nbase + st + j0;
                a1s[r][h][s] = nbase + st + j1;
            }
        }
    }
    __syncthreads();

    // ---- phase 2: vectorized gather+accumulate, one thread per (r,h,d4) ----
    {
        const int r   = t >> 6;
        const int rem = t & 63;
        const int h   = rem >> 3;
        const int d4  = rem & 7;

        const float4* v4 = reinterpret_cast<const float4*>(value);
        const int voff = h * 8 + d4;     // float4 offset within a value row

        float4 acc = make_float4(0.f, 0.f, 0.f, 0.f);
        #pragma unroll
        for (int s = 0; s < 16; ++s) {
            const float w0 = w0s[r][h][s];
            const float w1 = w1s[r][h][s];
            const float4 v0 = v4[(size_t)a0s[r][h][s] * 64 + voff];
            const float4 v1 = v4[(size_t)a1s[r][h][s] * 64 + voff];
            acc.x += w0 * v0.x + w1 * v1.x;
            acc.y += w0 * v0.y + w1 * v1.y;
            acc.z += w0 * v0.z + w1 * v1.z;
            acc.w += w0 * v0.w + w1 * v1.w;
        }
        reinterpret_cast<float4*>(outattn)[(size_t)(b0 + r) * 64 + voff] = acc;
    }
}

extern "C" void kernel_launch(void* const* d_in, const int* in_sizes, int n_in,
                              void* d_out, int out_size, void* d_ws, size_t ws_size,
                              hipStream_t stream) {
    const float* query  = (const float*)d_in[0];
    const float* refp   = (const float*)d_in[1];
    const float* inflat = (const float*)d_in[2];
    const int*   shapes = (const int*)d_in[3];
    const int*   starts = (const int*)d_in[4];
    const float* W_off  = (const float*)d_in[5];
    const float* b_off  = (const float*)d_in[6];
    const float* W_attn = (const float*)d_in[7];
    const float* b_attn = (const float*)d_in[8];
    const float* W_val  = (const float*)d_in[9];
    const float* b_val  = (const float*)d_in[10];
    const float* W_out  = (const float*)d_in[11];
    const float* b_out  = (const float*)d_in[12];
    float* out = (float*)d_out;

    float* value   = (float*)d_ws;                         // NROWS*256 f32 = 15.7 MB
    float* offattn = value + (size_t)NROWS * DMODEL;       // NROWS*256 f32 = 15.7 MB

    const dim3 blk(256);

    // value = input_flatten @ W_val + b_val
    gemm_f32<<<dim3(DMODEL / BN, NROWS / BM), blk, 0, stream>>>(
        inflat, W_val, b_val, value, NROWS, DMODEL, DMODEL, DMODEL, 0);

    // offattn[:, :128] = query @ W_off + b_off
    gemm_f32<<<dim3(128 / BN, NROWS / BM), blk, 0, stream>>>(
        query, W_off, b_off, offattn, NROWS, 128, DMODEL, DMODEL, 0);

    // offattn[:, 128:] = query @ W_attn + b_attn
    gemm_f32<<<dim3(128 / BN, NROWS / BM), blk, 0, stream>>>(
        query, W_attn, b_attn, offattn, NROWS, 128, DMODEL, DMODEL, 128);

    // softmax + sampling, in-place over offattn rows
    sample_k<<<NROWS / RPB, blk, 0, stream>>>(value, offattn, refp, shapes, starts, offattn);

    // out = outattn @ W_out + b_out
    gemm_f32<<<dim3(DMODEL / BN, NROWS / BM), blk, 0, stream>>>(
        offattn, W_out, b_out, out, NROWS, DMODEL, DMODEL, DMODEL, 0);
}

// Round 3
// 74.787 us; speedup vs baseline: 2.2083x; 1.7550x over previous
//
#include <hip/hip_runtime.h>
#include <hip/hip_bf16.h>

// Problem constants (from reference)
#define NB    4
#define LQ    3840
#define DMODEL 256
#define NH    8
#define NL    4
#define NP    4
#define DH    32
#define LIN   3840
#define NROWS (NB * LQ)     // 15360

typedef short          bf16x8 __attribute__((ext_vector_type(8)));
typedef float          f32x4  __attribute__((ext_vector_type(4)));
typedef unsigned short u16x8  __attribute__((ext_vector_type(8)));
typedef unsigned short u16x4  __attribute__((ext_vector_type(4)));

__device__ __forceinline__ unsigned short f2bf(float x) {
    __hip_bfloat16 h = __float2bfloat16(x);
    return *reinterpret_cast<unsigned short*>(&h);
}

__device__ __forceinline__ void gload_lds16(const unsigned short* g, unsigned short* l) {
    __builtin_amdgcn_global_load_lds(
        (const __attribute__((address_space(1))) unsigned int*)g,
        (__attribute__((address_space(3))) unsigned int*)l, 16, 0, 0);
}

// Row swizzle: physical_byte = logical_byte ^ ((row&7)<<4). Applied at write time
// (convert kernels / sample_k), undone at ds_read time in the GEMM. Keeps
// global_load_lds destinations linear (rule #21: swizzle both sides or neither).

// ---------------- convert f32 [rows][256] -> swizzled bf16 [rows][256] ----------------
__global__ __launch_bounds__(256) void convert_A(
    const float* __restrict__ in, unsigned short* __restrict__ out)
{
    const int tau = blockIdx.x * 256 + threadIdx.x;  // one thread per 8 elems
    const int row = tau >> 5;
    const int j   = tau & 31;
    const float4* p = reinterpret_cast<const float4*>(in + (size_t)row * 256 + j * 8);
    const float4 v0 = p[0];
    const float4 v1 = p[1];
    u16x8 r;
    r[0] = f2bf(v0.x); r[1] = f2bf(v0.y); r[2] = f2bf(v0.z); r[3] = f2bf(v0.w);
    r[4] = f2bf(v1.x); r[5] = f2bf(v1.y); r[6] = f2bf(v1.z); r[7] = f2bf(v1.w);
    const int swz = (j * 16) ^ ((row & 7) << 4);     // byte offset within 512B row
    *reinterpret_cast<u16x8*>(out + (size_t)row * 256 + (swz >> 1)) = r;
}

// ---------------- convert + transpose weights -> swizzled bf16 [N][K] ----------------
__global__ __launch_bounds__(256) void convert_W(
    const float* __restrict__ Wv, const float* __restrict__ Wo,
    const float* __restrict__ Wa, const float* __restrict__ Wout,
    const float* __restrict__ bo, const float* __restrict__ ba,
    unsigned short* __restrict__ WvT, unsigned short* __restrict__ WcT,
    unsigned short* __restrict__ WoutT, float* __restrict__ bcat)
{
    const int n = blockIdx.x;    // output row (original col)
    const int k = threadIdx.x;
    const int idx = n * 256 + ((((2 * k) ^ ((n & 7) << 4))) >> 1);
    WvT[idx]   = f2bf(Wv[k * 256 + n]);
    WoutT[idx] = f2bf(Wout[k * 256 + n]);
    const float wc = (n < 128) ? Wo[k * 128 + n] : Wa[k * 128 + (n - 128)];
    WcT[idx] = f2bf(wc);
    if (k == 0) bcat[n] = (n < 128) ? bo[n] : ba[n - 128];
}

// ---------------- bf16 MFMA GEMM: C = A(Mx256) @ Bt^T(256xN) + bias ----------------
// A, Bt: swizzled bf16 rows of K=256. Tile 128x128, BK=64, 4 waves (2x2).
__global__ __launch_bounds__(256) void gemm_bf16(
    const unsigned short* __restrict__ A,
    const unsigned short* __restrict__ Bt,
    const float* __restrict__ bias,
    float* __restrict__ C, int ldc, int coff)
{
    __shared__ unsigned short As[128 * 64];   // [row][64 k-slice], swizzled bytes
    __shared__ unsigned short Bs[128 * 64];

    const int t  = threadIdx.x;
    const int l  = t & 63;
    const int w  = t >> 6;
    const int m0 = blockIdx.y * 128;
    const int n0 = blockIdx.x * 128;
    const int wm = w >> 1, wn = w & 1;

    f32x4 acc[4][4] = {};

    for (int k0 = 0; k0 < 256; k0 += 64) {
        // stage: 16 chunks of 1KB each for A and B; wave w takes chunks 4w..4w+3
        #pragma unroll
        for (int j = 0; j < 4; ++j) {
            const int c    = w * 4 + j;
            const int rowA = c * 8 + (l >> 3);
            const int kofs = k0 + (l & 7) * 8;              // ushort offset
            gload_lds16(A  + (size_t)(m0 + rowA) * 256 + kofs, &As[c * 512]);
            gload_lds16(Bt + (size_t)(n0 + rowA) * 256 + kofs, &Bs[c * 512]);
        }
        __syncthreads();   // compiler drains vmcnt(0) before s_barrier

        #pragma unroll
        for (int kk = 0; kk < 2; ++kk) {
            const int koff = (kk * 64 + (l >> 4) * 16) ^ ((l & 7) << 4); // byte in 128B row
            bf16x8 af[4], bfr[4];
            #pragma unroll
            for (int mf = 0; mf < 4; ++mf) {
                const int row = wm * 64 + mf * 16 + (l & 15);
                af[mf] = *reinterpret_cast<const bf16x8*>(&As[row * 64 + (koff >> 1)]);
            }
            #pragma unroll
            for (int nf = 0; nf < 4; ++nf) {
                const int row = wn * 64 + nf * 16 + (l & 15);
                bfr[nf] = *reinterpret_cast<const bf16x8*>(&Bs[row * 64 + (koff >> 1)]);
            }
            #pragma unroll
            for (int mf = 0; mf < 4; ++mf)
                #pragma unroll
                for (int nf = 0; nf < 4; ++nf)
                    acc[mf][nf] = __builtin_amdgcn_mfma_f32_16x16x32_bf16(
                        af[mf], bfr[nf], acc[mf][nf], 0, 0, 0);
        }
        __syncthreads();
    }

    // epilogue: C/D layout col=lane&15, row=(lane>>4)*4+reg (m89-verified)
    float bv[4];
    #pragma unroll
    for (int nf = 0; nf < 4; ++nf)
        bv[nf] = bias[n0 + wn * 64 + nf * 16 + (l & 15)];

    #pragma unroll
    for (int mf = 0; mf < 4; ++mf) {
        #pragma unroll
        for (int nf = 0; nf < 4; ++nf) {
            const int col = n0 + wn * 64 + nf * 16 + (l & 15);
            #pragma unroll
            for (int q = 0; q < 4; ++q) {
                const int row = m0 + wm * 64 + mf * 16 + (l >> 4) * 4 + q;
                C[(size_t)row * ldc + coff + col] = acc[mf][nf][q] + bv[nf];
            }
        }
    }
}

// ---------------- fused softmax + deformable sampling (phase-split) ----------------
#define RPB 4

__global__ __launch_bounds__(256) void sample_k(
    const float* __restrict__ value,     // [NB][LIN][256] f32
    const float* __restrict__ offattn,   // [NROWS][256] f32
    const float* __restrict__ refp,      // [NB][LQ][NL]
    const int*   __restrict__ shapes,
    const int*   __restrict__ starts,
    unsigned short* __restrict__ outbf)  // [NROWS][256] bf16, swizzled rows
{
    __shared__ float row[RPB * 256];
    __shared__ float refs[RPB][NL];
    __shared__ float w0s[RPB][NH][16];
    __shared__ float w1s[RPB][NH][16];
    __shared__ int   a0s[RPB][NH][16];
    __shared__ int   a1s[RPB][NH][16];
    __shared__ int   shp[NL], stt[NL];

    const int t  = threadIdx.x;
    const int b0 = blockIdx.x * RPB;

    reinterpret_cast<float4*>(row)[t] =
        reinterpret_cast<const float4*>(offattn + (size_t)b0 * 256)[t];
    if (t < RPB * NL)
        refs[t >> 2][t & 3] = refp[(size_t)(b0 + (t >> 2)) * NL + (t & 3)];
    if (t >= 32 && t < 32 + NL) { shp[t - 32] = shapes[t - 32]; stt[t - 32] = starts[t - 32]; }
    __syncthreads();

    // ---- phase 1: scalar sample math, one thread per (r,h) ----
    if (t < RPB * NH) {
        const int r = t >> 3;
        const int h = t & 7;
        const int n = (b0 + r) / LQ;
        const int nbase = n * LIN;

        const float* lg = &row[r * 256 + 128 + h * 16];
        const float* of = &row[r * 256 + h * 16];

        float mx = lg[0];
        #pragma unroll
        for (int i = 1; i < 16; ++i) mx = fmaxf(mx, lg[i]);
        float e[16];
        float sum = 0.f;
        #pragma unroll
        for (int i = 0; i < 16; ++i) { e[i] = __expf(lg[i] - mx); sum += e[i]; }
        const float rsum = 1.f / sum;

        #pragma unroll
        for (int l = 0; l < NL; ++l) {
            const float T   = (float)shp[l];
            const float ref = refs[r][l];
            const int Tm1 = shp[l] - 1;
            const int st  = stt[l];
            #pragma unroll
            for (int p = 0; p < NP; ++p) {
                const int s = l * NP + p;
                const float aw  = e[s] * rsum;
                const float off = of[s];
                const float loc = ref + off / T;     // mimic reference rounding
                const float c   = loc * T - 0.5f;
                const float fl  = floorf(c);
                const float wgt = c - fl;
                const int i0 = (int)fl;
                const int j0 = min(max(i0, 0), Tm1);
                const int j1 = min(max(i0 + 1, 0), Tm1);
                w0s[r][h][s] = aw * (1.f - wgt);
                w1s[r][h][s] = aw * wgt;
                a0s[r][h][s] = nbase + st + j0;
                a1s[r][h][s] = nbase + st + j1;
            }
        }
    }
    __syncthreads();

    // ---- phase 2: vectorized gather+accumulate, one thread per (r,h,d4) ----
    {
        const int r   = t >> 6;
        const int rem = t & 63;
        const int h   = rem >> 3;
        const int d4  = rem & 7;

        const float4* v4 = reinterpret_cast<const float4*>(value);
        const int voff = h * 8 + d4;

        float4 acc = make_float4(0.f, 0.f, 0.f, 0.f);
        #pragma unroll
        for (int s = 0; s < 16; ++s) {
            const float w0 = w0s[r][h][s];
            const float w1 = w1s[r][h][s];
            const float4 v0 = v4[(size_t)a0s[r][h][s] * 64 + voff];
            const float4 v1 = v4[(size_t)a1s[r][h][s] * 64 + voff];
            acc.x += w0 * v0.x + w1 * v1.x;
            acc.y += w0 * v0.y + w1 * v1.y;
            acc.z += w0 * v0.z + w1 * v1.z;
            acc.w += w0 * v0.w + w1 * v1.w;
        }
        const int orow = b0 + r;
        u16x4 o;
        o[0] = f2bf(acc.x); o[1] = f2bf(acc.y); o[2] = f2bf(acc.z); o[3] = f2bf(acc.w);
        const int swz = (voff * 8) ^ ((orow & 7) << 4);
        *reinterpret_cast<u16x4*>(outbf + (size_t)orow * 256 + (swz >> 1)) = o;
    }
}

extern "C" void kernel_launch(void* const* d_in, const int* in_sizes, int n_in,
                              void* d_out, int out_size, void* d_ws, size_t ws_size,
                              hipStream_t stream) {
    const float* query  = (const float*)d_in[0];
    const float* refp   = (const float*)d_in[1];
    const float* inflat = (const float*)d_in[2];
    const int*   shapes = (const int*)d_in[3];
    const int*   starts = (const int*)d_in[4];
    const float* W_off  = (const float*)d_in[5];
    const float* b_off  = (const float*)d_in[6];
    const float* W_attn = (const float*)d_in[7];
    const float* b_attn = (const float*)d_in[8];
    const float* W_val  = (const float*)d_in[9];
    const float* b_val  = (const float*)d_in[10];
    const float* W_out  = (const float*)d_in[11];
    const float* b_out  = (const float*)d_in[12];
    float* out = (float*)d_out;

    // ws layout
    char* ws = (char*)d_ws;
    const size_t F32MAT = (size_t)NROWS * 256 * 4;   // 15,728,640
    const size_t BFMAT  = (size_t)NROWS * 256 * 2;   //  7,864,320
    float*          value   = (float*)ws;
    float*          offattn = (float*)(ws + F32MAT);
    unsigned short* Aq      = (unsigned short*)(ws + 2 * F32MAT);
    unsigned short* Ain     = (unsigned short*)(ws + 2 * F32MAT + BFMAT);
    unsigned short* outbf   = Ain;                   // alias: Ain dead after value GEMM
    unsigned short* WvT     = (unsigned short*)(ws + 2 * F32MAT + 2 * BFMAT);
    unsigned short* WcT     = WvT + 65536;
    unsigned short* WoutT   = WcT + 65536;
    float*          bcat    = (float*)(WoutT + 65536);

    const dim3 blk(256);

    convert_W<<<256, blk, 0, stream>>>(W_val, W_off, W_attn, W_out, b_off, b_attn,
                                       WvT, WcT, WoutT, bcat);
    convert_A<<<NROWS * 32 / 256, blk, 0, stream>>>(inflat, Ain);
    convert_A<<<NROWS * 32 / 256, blk, 0, stream>>>(query, Aq);

    // value = inflat @ W_val + b_val   (f32 out)
    gemm_bf16<<<dim3(2, 120), blk, 0, stream>>>(Ain, WvT, b_val, value, 256, 0);
    // offattn = query @ [W_off|W_attn] + [b_off|b_attn]
    gemm_bf16<<<dim3(2, 120), blk, 0, stream>>>(Aq, WcT, bcat, offattn, 256, 0);
    // softmax + sampling -> swizzled bf16
    sample_k<<<NROWS / RPB, blk, 0, stream>>>(value, offattn, refp, shapes, starts, outbf);
    // out = sampled @ W_out + b_out  (f32 out)
    gemm_bf16<<<dim3(2, 120), blk, 0, stream>>>(outbf, WoutT, b_out, out, 256, 0);
}

// Round 4
// 55.911 us; speedup vs baseline: 2.9539x; 1.3376x over previous
//
#include <hip/hip_runtime.h>
#include <hip/hip_bf16.h>

// Problem constants
#define NB    4
#define LQ    3840
#define NH    8
#define NL    4
#define NP    4
#define LIN   3840
#define NROWS (NB * LQ)     // 15360

typedef short          bf16x8 __attribute__((ext_vector_type(8)));
typedef float          f32x4  __attribute__((ext_vector_type(4)));
typedef unsigned short u16x8  __attribute__((ext_vector_type(8)));
typedef unsigned short u16x4  __attribute__((ext_vector_type(4)));

__device__ __forceinline__ unsigned short f2bf(float x) {
    __hip_bfloat16 h = __float2bfloat16(x);
    return *reinterpret_cast<unsigned short*>(&h);
}
__device__ __forceinline__ float bf2f(unsigned short u) {
    return __uint_as_float(((unsigned int)u) << 16);
}
__device__ __forceinline__ void gload_lds16(const unsigned short* g, unsigned short* l) {
    __builtin_amdgcn_global_load_lds(
        (const __attribute__((address_space(1))) unsigned int*)g,
        (__attribute__((address_space(3))) unsigned int*)l, 16, 0, 0);
}

// Swizzle convention (verified in R3): physical_byte = logical_byte ^ ((row&7)<<4),
// closed within each 128B k-slice. GEMM frag reads undo it via ((l&7)<<4) since
// fragment row ≡ (l&15) mod 16 => row&7 == l&7.

// ---------------- convert + transpose weights -> swizzled bf16 [N][K] ----------------
__global__ __launch_bounds__(256) void convert_W(
    const float* __restrict__ Wv, const float* __restrict__ Wo,
    const float* __restrict__ Wa, const float* __restrict__ Wout,
    const float* __restrict__ bo, const float* __restrict__ ba,
    unsigned short* __restrict__ WvT, unsigned short* __restrict__ WcT,
    unsigned short* __restrict__ WoutT, float* __restrict__ bcat)
{
    const int n = blockIdx.x;    // output row (original col)
    const int k = threadIdx.x;
    const int idx = n * 256 + ((((2 * k) ^ ((n & 7) << 4))) >> 1);
    WvT[idx]   = f2bf(Wv[k * 256 + n]);
    WoutT[idx] = f2bf(Wout[k * 256 + n]);
    const float wc = (n < 128) ? Wo[k * 128 + n] : Wa[k * 128 + (n - 128)];
    WcT[idx] = f2bf(wc);
    if (k == 0) bcat[n] = (n < 128) ? bo[n] : ba[n - 128];
}

// ---------------- fused fwd GEMMs: z=0 value = inflat@WvT+bval (bf16 linear out)
//                                   z=1 offattn = query@WcT+bcat (f32 out)
// Tile 64x128, BK=64, 4 waves (2x2). A is f32, converted during reg-staging.
__global__ __launch_bounds__(256) void gemm_fwd(
    const float* __restrict__ Ain, const float* __restrict__ Aq,
    const unsigned short* __restrict__ WvT, const unsigned short* __restrict__ WcT,
    const float* __restrict__ bval, const float* __restrict__ bcat,
    unsigned short* __restrict__ valbf, float* __restrict__ offattn)
{
    __shared__ unsigned short As[64 * 64];
    __shared__ unsigned short Bs[128 * 64];

    const int t  = threadIdx.x;
    const int l  = t & 63;
    const int w  = t >> 6;
    const int m0 = blockIdx.y * 64;
    const int n0 = blockIdx.x * 128;
    const int z  = blockIdx.z;
    const int wm = w >> 1, wn = w & 1;

    const float* A            = z ? Aq   : Ain;
    const unsigned short* Bt  = z ? WcT  : WvT;

    f32x4 acc[2][4] = {};

    for (int k0 = 0; k0 < 256; k0 += 64) {
        // A: 64x64 f32 -> bf16, swizzled ds_write (8B per thread-iter)
        #pragma unroll
        for (int j = 0; j < 4; ++j) {
            const int e   = j * 256 + t;
            const int row = e >> 4;
            const int kq  = e & 15;
            const float4 v = *reinterpret_cast<const float4*>(
                A + (size_t)(m0 + row) * 256 + k0 + kq * 4);
            u16x4 r;
            r[0] = f2bf(v.x); r[1] = f2bf(v.y); r[2] = f2bf(v.z); r[3] = f2bf(v.w);
            const int byte = row * 128 + ((kq * 8) ^ ((row & 7) << 4));
            *reinterpret_cast<u16x4*>(&As[byte >> 1]) = r;
        }
        // B: 128 rows x 64 k, pre-swizzled source -> linear LDS via global_load_lds
        #pragma unroll
        for (int j = 0; j < 4; ++j) {
            const int c    = w * 4 + j;
            const int rowB = c * 8 + (l >> 3);
            const int kofs = k0 + (l & 7) * 8;
            gload_lds16(Bt + (size_t)(n0 + rowB) * 256 + kofs, &Bs[c * 512]);
        }
        __syncthreads();

        #pragma unroll
        for (int kk = 0; kk < 2; ++kk) {
            const int koff = (kk * 64 + (l >> 4) * 16) ^ ((l & 7) << 4);
            bf16x8 af[2], bfr[4];
            #pragma unroll
            for (int mf = 0; mf < 2; ++mf) {
                const int row = wm * 32 + mf * 16 + (l & 15);
                af[mf] = *reinterpret_cast<const bf16x8*>(&As[row * 64 + (koff >> 1)]);
            }
            #pragma unroll
            for (int nf = 0; nf < 4; ++nf) {
                const int row = wn * 64 + nf * 16 + (l & 15);
                bfr[nf] = *reinterpret_cast<const bf16x8*>(&Bs[row * 64 + (koff >> 1)]);
            }
            #pragma unroll
            for (int mf = 0; mf < 2; ++mf)
                #pragma unroll
                for (int nf = 0; nf < 4; ++nf)
                    acc[mf][nf] = __builtin_amdgcn_mfma_f32_16x16x32_bf16(
                        af[mf], bfr[nf], acc[mf][nf], 0, 0, 0);
        }
        __syncthreads();
    }

    // epilogue: C/D layout col=lane&15, row=(lane>>4)*4+reg
    const float* bias = z ? bcat : bval;
    float bv[4];
    #pragma unroll
    for (int nf = 0; nf < 4; ++nf)
        bv[nf] = bias[n0 + wn * 64 + nf * 16 + (l & 15)];

    #pragma unroll
    for (int mf = 0; mf < 2; ++mf) {
        #pragma unroll
        for (int nf = 0; nf < 4; ++nf) {
            const int col = n0 + wn * 64 + nf * 16 + (l & 15);
            #pragma unroll
            for (int q = 0; q < 4; ++q) {
                const int row = m0 + wm * 32 + mf * 16 + (l >> 4) * 4 + q;
                const float o = acc[mf][nf][q] + bv[nf];
                if (z == 0) valbf[(size_t)row * 256 + col] = f2bf(o);
                else        offattn[(size_t)row * 256 + col] = o;
            }
        }
    }
}

// ---------------- final GEMM: out = sampled(bf16 swz) @ WoutT + b_out ----------------
__global__ __launch_bounds__(256) void gemm_out(
    const unsigned short* __restrict__ Abf,
    const unsigned short* __restrict__ Bt,
    const float* __restrict__ bias,
    float* __restrict__ C)
{
    __shared__ unsigned short As[64 * 64];
    __shared__ unsigned short Bs[128 * 64];

    const int t  = threadIdx.x;
    const int l  = t & 63;
    const int w  = t >> 6;
    const int m0 = blockIdx.y * 64;
    const int n0 = blockIdx.x * 128;
    const int wm = w >> 1, wn = w & 1;

    f32x4 acc[2][4] = {};

    for (int k0 = 0; k0 < 256; k0 += 64) {
        #pragma unroll
        for (int j = 0; j < 6; ++j) {               // 24 chunks: 8 A + 16 B
            const int c = w * 6 + j;
            if (c < 8) {
                const int rowA = c * 8 + (l >> 3);
                gload_lds16(Abf + (size_t)(m0 + rowA) * 256 + k0 + (l & 7) * 8,
                            &As[c * 512]);
            } else {
                const int cb   = c - 8;
                const int rowB = cb * 8 + (l >> 3);
                gload_lds16(Bt + (size_t)(n0 + rowB) * 256 + k0 + (l & 7) * 8,
                            &Bs[cb * 512]);
            }
        }
        __syncthreads();

        #pragma unroll
        for (int kk = 0; kk < 2; ++kk) {
            const int koff = (kk * 64 + (l >> 4) * 16) ^ ((l & 7) << 4);
            bf16x8 af[2], bfr[4];
            #pragma unroll
            for (int mf = 0; mf < 2; ++mf) {
                const int row = wm * 32 + mf * 16 + (l & 15);
                af[mf] = *reinterpret_cast<const bf16x8*>(&As[row * 64 + (koff >> 1)]);
            }
            #pragma unroll
            for (int nf = 0; nf < 4; ++nf) {
                const int row = wn * 64 + nf * 16 + (l & 15);
                bfr[nf] = *reinterpret_cast<const bf16x8*>(&Bs[row * 64 + (koff >> 1)]);
            }
            #pragma unroll
            for (int mf = 0; mf < 2; ++mf)
                #pragma unroll
                for (int nf = 0; nf < 4; ++nf)
                    acc[mf][nf] = __builtin_amdgcn_mfma_f32_16x16x32_bf16(
                        af[mf], bfr[nf], acc[mf][nf], 0, 0, 0);
        }
        __syncthreads();
    }

    float bv[4];
    #pragma unroll
    for (int nf = 0; nf < 4; ++nf)
        bv[nf] = bias[n0 + wn * 64 + nf * 16 + (l & 15)];

    #pragma unroll
    for (int mf = 0; mf < 2; ++mf)
        #pragma unroll
        for (int nf = 0; nf < 4; ++nf) {
            const int col = n0 + wn * 64 + nf * 16 + (l & 15);
            #pragma unroll
            for (int q = 0; q < 4; ++q) {
                const int row = m0 + wm * 32 + mf * 16 + (l >> 4) * 4 + q;
                C[(size_t)row * 256 + col] = acc[mf][nf][q] + bv[nf];
            }
        }
}

// ---------------- fused softmax + deformable sampling ----------------
#define RPB 4

__global__ __launch_bounds__(256) void sample_k(
    const unsigned short* __restrict__ value, // [NB*LIN][256] bf16 linear
    const float* __restrict__ offattn,        // [NROWS][256] f32
    const float* __restrict__ refp,
    const int*   __restrict__ shapes,
    const int*   __restrict__ starts,
    unsigned short* __restrict__ outbf)       // [NROWS][256] bf16, swizzled rows
{
    __shared__ float row[RPB * 256];
    __shared__ float refs[RPB][NL];
    __shared__ float w0s[RPB][NH][16];
    __shared__ float w1s[RPB][NH][16];
    __shared__ int   a0s[RPB][NH][16];
    __shared__ int   a1s[RPB][NH][16];
    __shared__ int   shp[NL], stt[NL];

    const int t  = threadIdx.x;
    const int b0 = blockIdx.x * RPB;

    reinterpret_cast<float4*>(row)[t] =
        reinterpret_cast<const float4*>(offattn + (size_t)b0 * 256)[t];
    if (t < RPB * NL)
        refs[t >> 2][t & 3] = refp[(size_t)(b0 + (t >> 2)) * NL + (t & 3)];
    if (t >= 32 && t < 32 + NL) { shp[t - 32] = shapes[t - 32]; stt[t - 32] = starts[t - 32]; }
    __syncthreads();

    // phase 1: scalar sample math, one thread per (r,h)
    if (t < RPB * NH) {
        const int r = t >> 3;
        const int h = t & 7;
        const int n = (b0 + r) / LQ;
        const int nbase = n * LIN;

        const float* lg = &row[r * 256 + 128 + h * 16];
        const float* of = &row[r * 256 + h * 16];

        float mx = lg[0];
        #pragma unroll
        for (int i = 1; i < 16; ++i) mx = fmaxf(mx, lg[i]);
        float e[16];
        float sum = 0.f;
        #pragma unroll
        for (int i = 0; i < 16; ++i) { e[i] = __expf(lg[i] - mx); sum += e[i]; }
        const float rsum = 1.f / sum;

        #pragma unroll
        for (int lvl = 0; lvl < NL; ++lvl) {
            const float T   = (float)shp[lvl];
            const float ref = refs[r][lvl];
            const int Tm1 = shp[lvl] - 1;
            const int st  = stt[lvl];
            #pragma unroll
            for (int p = 0; p < NP; ++p) {
                const int s = lvl * NP + p;
                const float aw  = e[s] * rsum;
                const float off = of[s];
                const float loc = ref + off / T;     // mimic reference rounding
                const float c   = loc * T - 0.5f;
                const float fl  = floorf(c);
                const float wgt = c - fl;
                const int i0 = (int)fl;
                const int j0 = min(max(i0, 0), Tm1);
                const int j1 = min(max(i0 + 1, 0), Tm1);
                w0s[r][h][s] = aw * (1.f - wgt);
                w1s[r][h][s] = aw * wgt;
                a0s[r][h][s] = nbase + st + j0;
                a1s[r][h][s] = nbase + st + j1;
            }
        }
    }
    __syncthreads();

    // phase 2: bf16 gather + accumulate, one thread per (r,h,d4) -> 4 dims
    {
        const int r   = t >> 6;
        const int rem = t & 63;
        const int h   = rem >> 3;
        const int d4  = rem & 7;
        const int coff = h * 32 + d4 * 4;   // ushort offset within value row

        float4 acc = make_float4(0.f, 0.f, 0.f, 0.f);
        #pragma unroll
        for (int s = 0; s < 16; ++s) {
            const float w0 = w0s[r][h][s];
            const float w1 = w1s[r][h][s];
            const u16x4 v0 = *reinterpret_cast<const u16x4*>(
                value + (size_t)a0s[r][h][s] * 256 + coff);
            const u16x4 v1 = *reinterpret_cast<const u16x4*>(
                value + (size_t)a1s[r][h][s] * 256 + coff);
            acc.x += w0 * bf2f(v0[0]) + w1 * bf2f(v1[0]);
            acc.y += w0 * bf2f(v0[1]) + w1 * bf2f(v1[1]);
            acc.z += w0 * bf2f(v0[2]) + w1 * bf2f(v1[2]);
            acc.w += w0 * bf2f(v0[3]) + w1 * bf2f(v1[3]);
        }
        const int orow = b0 + r;
        u16x4 o;
        o[0] = f2bf(acc.x); o[1] = f2bf(acc.y); o[2] = f2bf(acc.z); o[3] = f2bf(acc.w);
        const int voff = h * 8 + d4;                       // float4-equivalent index
        const int swz  = (voff * 8) ^ ((orow & 7) << 4);   // byte within 512B row
        *reinterpret_cast<u16x4*>(outbf + (size_t)orow * 256 + (swz >> 1)) = o;
    }
}

extern "C" void kernel_launch(void* const* d_in, const int* in_sizes, int n_in,
                              void* d_out, int out_size, void* d_ws, size_t ws_size,
                              hipStream_t stream) {
    const float* query  = (const float*)d_in[0];
    const float* refp   = (const float*)d_in[1];
    const float* inflat = (const float*)d_in[2];
    const int*   shapes = (const int*)d_in[3];
    const int*   starts = (const int*)d_in[4];
    const float* W_off  = (const float*)d_in[5];
    const float* b_off  = (const float*)d_in[6];
    const float* W_attn = (const float*)d_in[7];
    const float* b_attn = (const float*)d_in[8];
    const float* W_val  = (const float*)d_in[9];
    const float* b_val  = (const float*)d_in[10];
    const float* W_out  = (const float*)d_in[11];
    const float* b_out  = (const float*)d_in[12];
    float* out = (float*)d_out;

    // ws layout
    char* ws = (char*)d_ws;
    const size_t F32MAT = (size_t)NROWS * 256 * 4;
    const size_t BFMAT  = (size_t)NROWS * 256 * 2;
    unsigned short* valbf   = (unsigned short*)ws;                       // 7.9 MB
    float*          offattn = (float*)(ws + BFMAT);                      // 15.7 MB
    unsigned short* outbf   = (unsigned short*)(ws + BFMAT + F32MAT);    // 7.9 MB
    unsigned short* WvT     = (unsigned short*)(ws + 2 * BFMAT + F32MAT);
    unsigned short* WcT     = WvT + 65536;
    unsigned short* WoutT   = WcT + 65536;
    float*          bcat    = (float*)(WoutT + 65536);

    const dim3 blk(256);

    convert_W<<<256, blk, 0, stream>>>(W_val, W_off, W_attn, W_out, b_off, b_attn,
                                       WvT, WcT, WoutT, bcat);
    // z=0: value(bf16) = inflat@WvT+b_val ; z=1: offattn(f32) = query@WcT+bcat
    gemm_fwd<<<dim3(2, 240, 2), blk, 0, stream>>>(inflat, query, WvT, WcT,
                                                  b_val, bcat, valbf, offattn);
    sample_k<<<NROWS / RPB, blk, 0, stream>>>(valbf, offattn, refp, shapes, starts, outbf);
    gemm_out<<<dim3(2, 240), blk, 0, stream>>>(outbf, WoutT, b_out, out);
}